// Round 2
// baseline (173.937 us; speedup 1.0000x reference)
//
#include <hip/hip_runtime.h>

// EfficientAdditiveAttention  B=8, L=512, D=128
//
// combined(q,k) = sum_d w_all[d]*tanh(zq_d + zk_d)  -> softmax_k -> @V
// tanh = 1 - 2/(1+e^{2(zq+zk)});  e^{2(zq+zk)} = Eq*Ek, Eq/Ek precomputed by
// the projection kernel. Softmax-invariant constants dropped. With
// w^ = -2*log2e*w_all:  p(k) = exp2( sum_d w^_d / (1+Eq_d*Ek_d) ).
//
// v14:
//  - PERMUTED d-layout for Eq/Ek/w^ (per-quad [d0,d2,d1,d3], applied at
//    proj store; sum over d is perm-invariant). Enables fully PACKED v2f
//    pass-A quad-rational: X=(e0,e2),Y=(e1,e3); D=X*Y=(d01,d23);
//    N=fma2(Wlo,Y,Whi*X); NU=N*swap(D); one rcp per 4d; packed accumulate.
//    ~19 ops/8d vs 28 scalar.
//  - Eq read directly from global with wave-uniform addresses (qa is
//    readfirstlane-uniform) -> s_load on scalar pipe; EqL LDS removed.
//  - pass-B p-broadcast overlays into Ekt (dead after pass A) behind one
//    __syncthreads(). LDS 50688 -> 34816 B => 4 blocks/CU,
//    __launch_bounds__(512,8) caps VGPR at 64.
//  - proj retiled 32->16 rows/tile (768 blocks): 1.5 -> 3 waves/SIMD for
//    the latency-bound staging GEMM.

#define BB 8
#define LL 512
#define DD 128
#define NROW (BB*LL)            // 4096 rows
#define MATN (NROW*DD)          // 524288 elements per matrix
#define KSPLIT 8

static constexpr float C1 = 2.8853900817779268f;    // 2*log2(e)
static constexpr float LOG2E = 1.4426950408889634f;
static constexpr float INV_SCALE = 0.08838834764831845f; // 1/sqrt(128)

typedef float v2f __attribute__((ext_vector_type(2)));

__device__ __forceinline__ float fast_exp2(float x) { return __builtin_amdgcn_exp2f(x); }
__device__ __forceinline__ float fast_rcp(float x)  { return __builtin_amdgcn_rcpf(x); }

__device__ __forceinline__ v2f mk2(float a, float b) { v2f r; r.x = a; r.y = b; return r; }

__device__ __forceinline__ v2f fma2(v2f a, v2f b, v2f c) {
#if __has_builtin(__builtin_elementwise_fma)
    return __builtin_elementwise_fma(a, b, c);
#else
    v2f r; r.x = fmaf(a.x, b.x, c.x); r.y = fmaf(a.y, b.y, c.y); return r;
#endif
}

// per-quad storage permutation: value for dim (base+j) stored at base+pmap[j]
__device__ __forceinline__ int dperm(int c) {
    const int pmap[4] = {0, 2, 1, 3};
    return (c & ~3) | pmap[c & 3];
}

// ---------------------------------------------------------------------------
// Projection: z = X @ W.T + b; outputs Eq=exp2(C1*z) (m=0, permuted cols),
// Ek=exp2(C1*z) (m=1, permuted cols), V=z (m=2, linear cols).
// 16x128 tiles, 768 blocks x 256 threads, packed-f32 inner dot.
// ---------------------------------------------------------------------------
__global__ __launch_bounds__(256) void proj_kernel(
    const float* __restrict__ query, const float* __restrict__ key,
    const float* __restrict__ value,
    const float* __restrict__ Wq, const float* __restrict__ bq,
    const float* __restrict__ Wk, const float* __restrict__ bk,
    const float* __restrict__ Wv, const float* __restrict__ bv,
    const float* __restrict__ wd, const float* __restrict__ wsg,
    const float* __restrict__ wtt, float* __restrict__ ws)
{
    __shared__ __align__(16) float Wl[128 * 66];   // 33792 B
    __shared__ __align__(16) float Xl[16 * 66];    //  4224 B

    const int bx = blockIdx.x;
    const int m  = bx >> 8;              // 0:Q 1:K 2:V  (256 row-tiles each)
    const int r0 = (bx & 255) * 16;
    const float* X    = (m == 0) ? query : (m == 1) ? key : value;
    const float* W    = (m == 0) ? Wq    : (m == 1) ? Wk  : Wv;
    const float* bias = (m == 0) ? bq    : (m == 1) ? bk  : bv;
    const int t = threadIdx.x;

    // w^ = -2*log2e*(1/sqrt(D) + wd + wsg + wtt)  -> ws tail, PERMUTED
    if (bx == 0 && t < 128) {
        ws[(size_t)3 * MATN + dperm(t)] =
            -2.0f * LOG2E * (INV_SCALE + wd[t] + wsg[t] + wtt[t]);
    }

    const int cg = t & 31;   // cols: cg + 32*j
    const int rg = t >> 5;   // rows: rg*2 + i

    v2f acc[2][4];
    #pragma unroll
    for (int j = 0; j < 4; ++j) {
        float bj = bias[cg + 32 * j];
        #pragma unroll
        for (int i = 0; i < 2; ++i) acc[i][j] = mk2(bj, 0.f);
    }

    const float4* Wsrc = (const float4*)W;
    const float4* Xsrc = (const float4*)X;

    for (int h = 0; h < 2; ++h) {            // K-dim halves (64 each)
        __syncthreads();
        #pragma unroll
        for (int j = 0; j < 8; ++j) {        // W half: 128 rows x 16 f4
            int g = t + j * 256;
            int c = g >> 4, f4 = g & 15;
            float4 v = Wsrc[c * 32 + h * 16 + f4];
            float* dst = &Wl[c * 66 + f4 * 4];
            *(float2*)dst       = make_float2(v.x, v.y);
            *(float2*)(dst + 2) = make_float2(v.z, v.w);
        }
        {                                    // X half: 16 rows x 16 f4
            int r = t >> 4, f4 = t & 15;
            float4 v = Xsrc[(r0 + r) * 32 + h * 16 + f4];
            float* dst = &Xl[r * 66 + f4 * 4];
            *(float2*)dst       = make_float2(v.x, v.y);
            *(float2*)(dst + 2) = make_float2(v.z, v.w);
        }
        __syncthreads();

        #pragma unroll 4
        for (int dg = 0; dg < 32; ++dg) {
            v2f bf[4];
            #pragma unroll
            for (int j = 0; j < 4; ++j)
                bf[j] = *(const v2f*)&Wl[(cg + 32 * j) * 66 + 2 * dg];
            v2f af[2];
            #pragma unroll
            for (int i = 0; i < 2; ++i)
                af[i] = *(const v2f*)&Xl[(rg * 2 + i) * 66 + 2 * dg];
            #pragma unroll
            for (int i = 0; i < 2; ++i)
                #pragma unroll
                for (int j = 0; j < 4; ++j)
                    acc[i][j] = fma2(af[i], bf[j], acc[i][j]);
        }
    }

    if (m == 2) {
        float* oV = ws + (size_t)2 * MATN;  // V: linear layout
        #pragma unroll
        for (int i = 0; i < 2; ++i) {
            int r = r0 + rg * 2 + i;
            #pragma unroll
            for (int j = 0; j < 4; ++j)
                oV[(size_t)r * DD + cg + 32 * j] = acc[i][j].x + acc[i][j].y;
        }
    } else {
        float* oE = ws + (size_t)m * MATN;  // Eq/Ek: permuted layout
        const int cp = dperm(cg);           // (cg&~3)|pmap[cg&3]
        #pragma unroll
        for (int i = 0; i < 2; ++i) {
            int r = r0 + rg * 2 + i;
            #pragma unroll
            for (int j = 0; j < 4; ++j)
                oE[(size_t)r * DD + cp + 32 * j] =
                    fast_exp2(C1 * (acc[i][j].x + acc[i][j].y));
        }
    }
}

// ---------------------------------------------------------------------------
// Attention main. 1024 blocks x 512 threads. Block = 32 q x one 64-k tile.
// Wave = 4 q. Ek in LDS [k][132] (permuted quads); w^ in LDS (permuted);
// Eq via wave-uniform global reads (scalar loads). Packed v2f quad-rational.
// Pass-B p-broadcast overlaid into Ekt after a barrier.
// ---------------------------------------------------------------------------
template <bool ATOMIC>
__global__ __launch_bounds__(512, 8) void attn_kernel(
    const float* __restrict__ ws, float* __restrict__ outp,
    float* __restrict__ psump)
{
    __shared__ __align__(16) float Ekt[64 * 132];   // 33792 B
    __shared__ __align__(16) float wl[128];         //   512 B

    const float* Eq  = ws;
    const float* Ek  = ws + (size_t)MATN;
    const float* Vp  = ws + (size_t)2 * MATN;

    const int bx   = blockIdx.x;               // 1024 blocks
    const int qblk = bx >> 3;                  // 0..127  (32 q each)
    const int kx   = bx & 7;                   // k-chunk (64 k)
    const int b    = qblk >> 4;                // 16 q-blocks per batch
    const int wave = __builtin_amdgcn_readfirstlane((int)threadIdx.x >> 6);
    const int lane = threadIdx.x & 63;
    const int qa   = qblk * 32 + wave * 4;     // wave-uniform (global q base)

    {   // stage Ek tile (64 k x 128 d) -> stride-132 rows; w^ -> wl
        const float4* sK = (const float4*)(Ek + (size_t)b * (LL * DD)
                                              + (size_t)kx * 64 * DD);
        #pragma unroll
        for (int r = 0; r < 4; ++r) {
            int g = (int)threadIdx.x + r * 512;    // 0..2047
            int row = g >> 5, c4 = g & 31;
            *(float4*)&Ekt[row * 132 + c4 * 4] = sK[g];
        }
        if (threadIdx.x < 32)
            ((float4*)wl)[threadIdx.x] =
                ((const float4*)(ws + (size_t)3 * MATN))[threadIdx.x];
    }
    __syncthreads();

    // ---- pass A: s(qa..qa+3, k = kx*64+lane); 8 d per step, packed v2f.
    // Quad layout [d0,d2,d1,d3]: lo=(v_d0,v_d2), hi=(v_d1,v_d3).
    const float* krow = &Ekt[lane * 132];
    const float4* wl4 = (const float4*)wl;
    const float* eqq  = Eq + (size_t)qa * DD;  // wave-uniform -> s_load
    v2f S0 = mk2(0.f, 0.f), S1 = S0, S2 = S0, S3 = S0;

    #pragma unroll 2
    for (int ih = 0; ih < 16; ++ih) {          // d = 8*ih .. 8*ih+7
        float4 K0 = *(const float4*)(krow + 8 * ih);      // per-lane b128
        float4 K1 = *(const float4*)(krow + 8 * ih + 4);
        float4 W0 = wl4[2 * ih];                          // bcast b128
        float4 W1 = wl4[2 * ih + 1];
        v2f k0lo = mk2(K0.x, K0.y), k0hi = mk2(K0.z, K0.w);
        v2f k1lo = mk2(K1.x, K1.y), k1hi = mk2(K1.z, K1.w);
        v2f w0lo = mk2(W0.x, W0.y), w0hi = mk2(W0.z, W0.w);
        v2f w1lo = mk2(W1.x, W1.y), w1hi = mk2(W1.z, W1.w);
        // packed quad-rational: contributes sum_{4d} w_d/(1+Eq_d*Ek_d)
        #define QT(SS, QQ) { \
            float4 A0 = *(const float4*)(eqq + (QQ) * 128 + 8 * ih); \
            float4 A1 = *(const float4*)(eqq + (QQ) * 128 + 8 * ih + 4); \
            v2f X  = fma2(mk2(A0.x, A0.y), k0lo, mk2(1.f, 1.f)); \
            v2f Y  = fma2(mk2(A0.z, A0.w), k0hi, mk2(1.f, 1.f)); \
            v2f D  = X * Y;                       /* (d01,d23) */ \
            v2f N  = fma2(w0lo, Y, w0hi * X);     /* (n01,n23) */ \
            v2f NU = N * mk2(D.y, D.x); \
            float rr = fast_rcp(D.x * D.y); \
            SS = fma2(NU, mk2(rr, rr), SS); \
            v2f X1  = fma2(mk2(A1.x, A1.y), k1lo, mk2(1.f, 1.f)); \
            v2f Y1  = fma2(mk2(A1.z, A1.w), k1hi, mk2(1.f, 1.f)); \
            v2f D1  = X1 * Y1; \
            v2f N1  = fma2(w1lo, Y1, w1hi * X1); \
            v2f NU1 = N1 * mk2(D1.y, D1.x); \
            float rr1 = fast_rcp(D1.x * D1.y); \
            SS = fma2(NU1, mk2(rr1, rr1), SS); }
        QT(S0, 0) QT(S1, 1) QT(S2, 2) QT(S3, 3)
        #undef QT
    }
    float p0 = fast_exp2(S0.x + S0.y);   // lane holds p(qa+qq, k = kx*64+lane)
    float p1 = fast_exp2(S1.x + S1.y);
    float p2 = fast_exp2(S2.x + S2.y);
    float p3 = fast_exp2(S3.x + S3.y);

    // psum over this tile's 64 k
    float t0 = p0, t1 = p1, t2 = p2, t3 = p3;
    #pragma unroll
    for (int off = 32; off; off >>= 1) {
        t0 += __shfl_xor(t0, off);
        t1 += __shfl_xor(t1, off);
        t2 += __shfl_xor(t2, off);
        t3 += __shfl_xor(t3, off);
    }
    if (lane == 0) {
        if (ATOMIC) {
            atomicAdd(&psump[qa + 0], t0);
            atomicAdd(&psump[qa + 1], t1);
            atomicAdd(&psump[qa + 2], t2);
            atomicAdd(&psump[qa + 3], t3);
        } else {
            float* pp = psump + (size_t)kx * NROW + qa;
            pp[0] = t0; pp[1] = t1; pp[2] = t2; pp[3] = t3;
        }
    }

    // Ekt is dead once ALL waves finished pass A; overlay the p-broadcast
    // buffer into it (wave-private 256-float segments).
    __syncthreads();
    *(float4*)&Ekt[wave * 256 + 4 * lane] = make_float4(p0, p1, p2, p3);

    // ---- pass B: o += p * V ; lane = d-pair, p via uniform LDS bcast;
    // bounded batches of 8 V-loads (8 live float2) to avoid spill.
    const float2* __restrict__ Vg =
        (const float2*)(Vp + (size_t)b * (LL * DD) + (size_t)kx * 64 * DD);
    float2 o[4];
    #pragma unroll
    for (int qq = 0; qq < 4; ++qq) o[qq] = make_float2(0.f, 0.f);

    #pragma unroll
    for (int g = 0; g < 8; ++g) {
        float2 v[8];
        #pragma unroll
        for (int e = 0; e < 8; ++e)
            v[e] = Vg[(size_t)(8 * g + e) * 64 + lane];   // coalesced batch
        #pragma unroll
        for (int e = 0; e < 8; ++e) {
            int kidx = 8 * g + e;
            float4 pw = *(const float4*)&Ekt[wave * 256 + 4 * kidx]; // bcast
            o[0].x = fmaf(pw.x, v[e].x, o[0].x); o[0].y = fmaf(pw.x, v[e].y, o[0].y);
            o[1].x = fmaf(pw.y, v[e].x, o[1].x); o[1].y = fmaf(pw.y, v[e].y, o[1].y);
            o[2].x = fmaf(pw.z, v[e].x, o[2].x); o[2].y = fmaf(pw.z, v[e].y, o[2].y);
            o[3].x = fmaf(pw.w, v[e].x, o[3].x); o[3].y = fmaf(pw.w, v[e].y, o[3].y);
        }
    }

    const int d2 = 2 * lane;
    if (ATOMIC) {
        #pragma unroll
        for (int qq = 0; qq < 4; ++qq) {
            atomicAdd(&outp[(size_t)(qa + qq) * DD + d2],     o[qq].x);
            atomicAdd(&outp[(size_t)(qa + qq) * DD + d2 + 1], o[qq].y);
        }
    } else {
        float* base = outp + (size_t)kx * MATN;
        #pragma unroll
        for (int qq = 0; qq < 4; ++qq)
            *(float2*)&base[(size_t)(qa + qq) * DD + d2] = o[qq];
    }
}

// ---------------------------------------------------------------------------
// Fused reduce + normalize: out[q,d] = (sum_kx part[kx][q,d]) / (sum_kx psumP)
// float4-wide: 512 blocks x 256 threads over 131072 float4s.
// ---------------------------------------------------------------------------
__global__ __launch_bounds__(256) void reduce_kernel(
    const float* __restrict__ part, const float* __restrict__ psumP,
    float* __restrict__ out)
{
    int t = blockIdx.x * 256 + threadIdx.x;    // 131072 float4s
    const float4* p4 = (const float4*)part;
    float4 acc = make_float4(0.f, 0.f, 0.f, 0.f);
    #pragma unroll
    for (int kx = 0; kx < KSPLIT; ++kx) {
        float4 v = p4[(size_t)kx * (MATN / 4) + t];
        acc.x += v.x; acc.y += v.y; acc.z += v.z; acc.w += v.w;
    }
    int q = t >> 5;                            // 32 float4 per row
    float s = 0.f;
    #pragma unroll
    for (int kx = 0; kx < KSPLIT; ++kx) s += psumP[(size_t)kx * NROW + q];
    float inv = fast_rcp(s);
    ((float4*)out)[t] = make_float4(acc.x * inv, acc.y * inv,
                                    acc.z * inv, acc.w * inv);
}

// ---------------------------------------------------------------------------
__global__ __launch_bounds__(256) void norm_kernel(
    float* __restrict__ out, const float* __restrict__ psumG)
{
    int t = blockIdx.x * 256 + threadIdx.x;    // 262144 float2s
    float2* o2 = (float2*)out;
    int q = t >> 6;
    float inv = fast_rcp(psumG[q]);
    float2 v = o2[t];
    o2[t] = make_float2(v.x * inv, v.y * inv);
}

// ---------------------------------------------------------------------------
extern "C" void kernel_launch(void* const* d_in, const int* in_sizes, int n_in,
                              void* d_out, int out_size, void* d_ws, size_t ws_size,
                              hipStream_t stream) {
    const float* query = (const float*)d_in[0];
    const float* key_  = (const float*)d_in[1];
    const float* value = (const float*)d_in[2];
    const float* Wq    = (const float*)d_in[3];
    const float* bq    = (const float*)d_in[4];
    const float* Wk    = (const float*)d_in[5];
    const float* bk    = (const float*)d_in[6];
    const float* Wv    = (const float*)d_in[7];
    const float* bv    = (const float*)d_in[8];
    const float* wd    = (const float*)d_in[9];
    // d_in[10]/[12]/[14] = b_delta/b_sigma/b_theta: softmax-invariant, dropped
    const float* wsg   = (const float*)d_in[11];
    const float* wtt   = (const float*)d_in[13];
    float* ws = (float*)d_ws;
    float* out = (float*)d_out;

    // ws layout: Eq | Ek | V | w^(128) | psumP(8*NROW) | part(8*MATN)
    const size_t off_psum = (size_t)3 * MATN + 128;
    const size_t off_part = off_psum + (size_t)KSPLIT * NROW;
    const size_t need = (off_part + (size_t)KSPLIT * MATN) * sizeof(float);

    proj_kernel<<<768, 256, 0, stream>>>(query, key_, value,
                                         Wq, bq, Wk, bk, Wv, bv,
                                         wd, wsg, wtt, ws);
    if (ws_size >= need) {
        float* psumP = ws + off_psum;
        float* part  = ws + off_part;
        attn_kernel<false><<<1024, 512, 0, stream>>>(ws, part, psumP);
        reduce_kernel<<<512, 256, 0, stream>>>(part, psumP, out);
    } else {
        float* psumG = ws + off_psum;
        hipMemsetAsync(out, 0, (size_t)out_size * sizeof(float), stream);
        hipMemsetAsync(psumG, 0, (size_t)NROW * sizeof(float), stream);
        attn_kernel<true><<<1024, 512, 0, stream>>>(ws, out, psumG);
        norm_kernel<<<1024, 256, 0, stream>>>(out, psumG);
    }
}

// Round 3
// 132.929 us; speedup vs baseline: 1.3085x; 1.3085x over previous
//
#include <hip/hip_runtime.h>

// EfficientAdditiveAttention  B=8, L=512, D=128
//
// combined(q,k) = sum_d w_all[d]*tanh(zq_d + zk_d)  -> softmax_k -> @V
// tanh = 1 - 2/(1+e^{2(zq+zk)});  e^{2(zq+zk)} = Eq*Ek, Eq/Ek precomputed by
// the projection kernel. Softmax-invariant constants dropped. With
// w^ = -2*log2e*w_all:  p(k) = exp2( sum_d w^_d / (1+Eq_d*Ek_d) ).
//
// v15 = R1 memory plan + R2 packed math (R2's global-Eq experiment spilled
// to scratch: WRITE_SIZE 34->108 MB, VALUBusy 57->28%; reverted):
//  - Eq staged in wave-private LDS (EqL), pass A reads it via uniform
//    ds_read_b128 broadcasts (R1-proven: VGPR 40, no spill, 48.2us).
//  - PERMUTED d-layout [d0,d2,d1,d3] for Eq/Ek/w^ (R2-verified correct)
//    enables fully packed v2f quad-rational: one rcp per 4 d, all muls/fmas
//    as v_pk_*_f32. ~30% fewer pass-A VALU ops than R1 scalar.
//  - pass B packed too: o[] as v2f, 4 fma2 per V element (was 8 fmaf).
//  - proj back to 384 blocks x 32-row tiles (R2's 16-row retile worsened
//    LDS-read:FMA ratio and doubled W restaging; +6us).
//  - launch_bounds(512,6): 3 blocks/CU at LDS 50688, VGPR cap 85.

#define BB 8
#define LL 512
#define DD 128
#define NROW (BB*LL)            // 4096 rows
#define MATN (NROW*DD)          // 524288 elements per matrix
#define KSPLIT 8

static constexpr float C1 = 2.8853900817779268f;    // 2*log2(e)
static constexpr float LOG2E = 1.4426950408889634f;
static constexpr float INV_SCALE = 0.08838834764831845f; // 1/sqrt(128)

typedef float v2f __attribute__((ext_vector_type(2)));

__device__ __forceinline__ float fast_exp2(float x) { return __builtin_amdgcn_exp2f(x); }
__device__ __forceinline__ float fast_rcp(float x)  { return __builtin_amdgcn_rcpf(x); }

__device__ __forceinline__ v2f mk2(float a, float b) { v2f r; r.x = a; r.y = b; return r; }

__device__ __forceinline__ v2f fma2(v2f a, v2f b, v2f c) {
#if __has_builtin(__builtin_elementwise_fma)
    return __builtin_elementwise_fma(a, b, c);
#else
    v2f r; r.x = fmaf(a.x, b.x, c.x); r.y = fmaf(a.y, b.y, c.y); return r;
#endif
}

// per-quad storage permutation: value for dim (base+j) stored at base+pmap[j]
__device__ __forceinline__ int dperm(int c) {
    const int pmap[4] = {0, 2, 1, 3};
    return (c & ~3) | pmap[c & 3];
}

// ---------------------------------------------------------------------------
// Projection: z = X @ W.T + b; outputs Eq=exp2(C1*z) (m=0, permuted cols),
// Ek=exp2(C1*z) (m=1, permuted cols), V=z (m=2, linear cols).
// 32x128 tiles, 384 blocks x 256 threads, packed-f32 inner dot.
// ---------------------------------------------------------------------------
__global__ __launch_bounds__(256) void proj_kernel(
    const float* __restrict__ query, const float* __restrict__ key,
    const float* __restrict__ value,
    const float* __restrict__ Wq, const float* __restrict__ bq,
    const float* __restrict__ Wk, const float* __restrict__ bk,
    const float* __restrict__ Wv, const float* __restrict__ bv,
    const float* __restrict__ wd, const float* __restrict__ wsg,
    const float* __restrict__ wtt, float* __restrict__ ws)
{
    __shared__ __align__(16) float Wl[128 * 66];   // 33792 B
    __shared__ __align__(16) float Xl[32 * 66];    //  8448 B

    const int bx = blockIdx.x;
    const int m  = bx >> 7;              // 0:Q 1:K 2:V  (128 row-tiles each)
    const int r0 = (bx & 127) * 32;
    const float* X    = (m == 0) ? query : (m == 1) ? key : value;
    const float* W    = (m == 0) ? Wq    : (m == 1) ? Wk  : Wv;
    const float* bias = (m == 0) ? bq    : (m == 1) ? bk  : bv;
    const int t = threadIdx.x;

    // w^ = -2*log2e*(1/sqrt(D) + wd + wsg + wtt)  -> ws tail, PERMUTED
    if (bx == 0 && t < 128) {
        ws[(size_t)3 * MATN + dperm(t)] =
            -2.0f * LOG2E * (INV_SCALE + wd[t] + wsg[t] + wtt[t]);
    }

    const int cg = t & 31;   // cols: cg + 32*j
    const int rg = t >> 5;   // rows: rg*4 + i

    v2f acc[4][4];
    #pragma unroll
    for (int j = 0; j < 4; ++j) {
        float bj = bias[cg + 32 * j];
        #pragma unroll
        for (int i = 0; i < 4; ++i) acc[i][j] = mk2(bj, 0.f);
    }

    const float4* Wsrc = (const float4*)W;
    const float4* Xsrc = (const float4*)X;

    for (int h = 0; h < 2; ++h) {            // K-dim halves (64 each)
        __syncthreads();
        #pragma unroll
        for (int j = 0; j < 8; ++j) {        // W half: 128 rows x 16 f4
            int g = t + j * 256;
            int c = g >> 4, f4 = g & 15;
            float4 v = Wsrc[c * 32 + h * 16 + f4];
            float* dst = &Wl[c * 66 + f4 * 4];
            *(float2*)dst       = make_float2(v.x, v.y);
            *(float2*)(dst + 2) = make_float2(v.z, v.w);
        }
        #pragma unroll
        for (int j = 0; j < 2; ++j) {        // X half: 32 rows x 16 f4
            int g = t + j * 256;
            int r = g >> 4, f4 = g & 15;
            float4 v = Xsrc[(r0 + r) * 32 + h * 16 + f4];
            float* dst = &Xl[r * 66 + f4 * 4];
            *(float2*)dst       = make_float2(v.x, v.y);
            *(float2*)(dst + 2) = make_float2(v.z, v.w);
        }
        __syncthreads();

        #pragma unroll 4
        for (int dg = 0; dg < 32; ++dg) {
            v2f bf[4];
            #pragma unroll
            for (int j = 0; j < 4; ++j)
                bf[j] = *(const v2f*)&Wl[(cg + 32 * j) * 66 + 2 * dg];
            v2f af[4];
            #pragma unroll
            for (int i = 0; i < 4; ++i)
                af[i] = *(const v2f*)&Xl[(rg * 4 + i) * 66 + 2 * dg];
            #pragma unroll
            for (int i = 0; i < 4; ++i)
                #pragma unroll
                for (int j = 0; j < 4; ++j)
                    acc[i][j] = fma2(af[i], bf[j], acc[i][j]);
        }
    }

    if (m == 2) {
        float* oV = ws + (size_t)2 * MATN;  // V: linear layout
        #pragma unroll
        for (int i = 0; i < 4; ++i) {
            int r = r0 + rg * 4 + i;
            #pragma unroll
            for (int j = 0; j < 4; ++j)
                oV[(size_t)r * DD + cg + 32 * j] = acc[i][j].x + acc[i][j].y;
        }
    } else {
        float* oE = ws + (size_t)m * MATN;  // Eq/Ek: permuted layout
        const int cp = dperm(cg);           // quad-perm; +32*j keeps quads
        #pragma unroll
        for (int i = 0; i < 4; ++i) {
            int r = r0 + rg * 4 + i;
            #pragma unroll
            for (int j = 0; j < 4; ++j)
                oE[(size_t)r * DD + cp + 32 * j] =
                    fast_exp2(C1 * (acc[i][j].x + acc[i][j].y));
        }
    }
}

// ---------------------------------------------------------------------------
// Attention main. 1024 blocks x 512 threads. Block = 32 q x one 64-k tile.
// Wave = 4 q. Ek in LDS [k][132] (permuted quads); w^ in LDS (permuted);
// Eq in wave-private LDS segment, read via uniform ds_read_b128 broadcast.
// Packed v2f quad-rational pass A; packed pass B; p-broadcast reuses EqL.
// ---------------------------------------------------------------------------
template <bool ATOMIC>
__global__ __launch_bounds__(512, 6) void attn_kernel(
    const float* __restrict__ ws, float* __restrict__ outp,
    float* __restrict__ psump)
{
    __shared__ __align__(16) float Ekt[64 * 132];   // 33792 B
    __shared__ __align__(16) float wl[128];         //   512 B
    __shared__ __align__(16) float EqL[8 * 512];    // 16384 B (wave-private)

    const float* Eq  = ws;
    const float* Ek  = ws + (size_t)MATN;
    const float* Vp  = ws + (size_t)2 * MATN;

    const int bx   = blockIdx.x;               // 1024 blocks
    const int qblk = bx >> 3;                  // 0..127  (32 q each)
    const int kx   = bx & 7;                   // k-chunk (64 k)
    const int b    = qblk >> 4;                // 16 q-blocks per batch
    const int wave = __builtin_amdgcn_readfirstlane((int)threadIdx.x >> 6);
    const int lane = threadIdx.x & 63;
    const int qa   = qblk * 32 + wave * 4;     // wave-uniform (global q base)
    const int eqo  = wave * 512;               // wave-private EqL base

    {   // stage Eq rows (4 q x 128 d, permuted quads) into wave's LDS segment
        const float4* EqW = (const float4*)(Eq + (size_t)qa * DD);
        float4 ea = EqW[2 * lane];
        float4 eb = EqW[2 * lane + 1];
        *(float4*)&EqL[eqo + 8 * lane]     = ea;
        *(float4*)&EqL[eqo + 8 * lane + 4] = eb;
    }

    {   // stage Ek tile (64 k x 128 d) -> stride-132 rows; w^ -> wl
        const float4* sK = (const float4*)(Ek + (size_t)b * (LL * DD)
                                              + (size_t)kx * 64 * DD);
        #pragma unroll
        for (int r = 0; r < 4; ++r) {
            int g = (int)threadIdx.x + r * 512;    // 0..2047
            int row = g >> 5, c4 = g & 31;
            *(float4*)&Ekt[row * 132 + c4 * 4] = sK[g];
        }
        if (threadIdx.x < 32)
            ((float4*)wl)[threadIdx.x] =
                ((const float4*)(ws + (size_t)3 * MATN))[threadIdx.x];
    }
    __syncthreads();

    // ---- pass A: s(qa..qa+3, k = kx*64+lane); 8 d per step, packed v2f.
    // Quad layout [d0,d2,d1,d3]: lo pair=(v_d0,v_d2), hi pair=(v_d1,v_d3).
    const float* krow = &Ekt[lane * 132];
    const float4* wl4 = (const float4*)wl;
    const float* eqp  = &EqL[eqo];             // uniform base -> bcast reads
    v2f S0 = mk2(0.f, 0.f), S1 = S0, S2 = S0, S3 = S0;

    #pragma unroll 2
    for (int ih = 0; ih < 16; ++ih) {          // d = 8*ih .. 8*ih+7
        float4 K0 = *(const float4*)(krow + 8 * ih);      // per-lane b128
        float4 K1 = *(const float4*)(krow + 8 * ih + 4);
        float4 W0 = wl4[2 * ih];                          // bcast b128
        float4 W1 = wl4[2 * ih + 1];
        v2f k0lo = mk2(K0.x, K0.y), k0hi = mk2(K0.z, K0.w);
        v2f k1lo = mk2(K1.x, K1.y), k1hi = mk2(K1.z, K1.w);
        v2f w0lo = mk2(W0.x, W0.y), w0hi = mk2(W0.z, W0.w);
        v2f w1lo = mk2(W1.x, W1.y), w1hi = mk2(W1.z, W1.w);
        // packed quad-rational: contributes sum_{4d} w_d/(1+Eq_d*Ek_d)
        #define QT(SS, QQ) { \
            float4 A0 = *(const float4*)(eqp + (QQ) * 128 + 8 * ih); \
            float4 A1 = *(const float4*)(eqp + (QQ) * 128 + 8 * ih + 4); \
            v2f X  = fma2(mk2(A0.x, A0.y), k0lo, mk2(1.f, 1.f)); \
            v2f Y  = fma2(mk2(A0.z, A0.w), k0hi, mk2(1.f, 1.f)); \
            v2f D  = X * Y;                       /* (d01,d23) */ \
            v2f N  = fma2(w0lo, Y, w0hi * X);     /* (n01,n23) */ \
            v2f NU = N * mk2(D.y, D.x); \
            float rr = fast_rcp(D.x * D.y); \
            SS = fma2(NU, mk2(rr, rr), SS); \
            v2f X1  = fma2(mk2(A1.x, A1.y), k1lo, mk2(1.f, 1.f)); \
            v2f Y1  = fma2(mk2(A1.z, A1.w), k1hi, mk2(1.f, 1.f)); \
            v2f D1  = X1 * Y1; \
            v2f N1  = fma2(w1lo, Y1, w1hi * X1); \
            v2f NU1 = N1 * mk2(D1.y, D1.x); \
            float rr1 = fast_rcp(D1.x * D1.y); \
            SS = fma2(NU1, mk2(rr1, rr1), SS); }
        QT(S0, 0) QT(S1, 1) QT(S2, 2) QT(S3, 3)
        #undef QT
    }
    float p0 = fast_exp2(S0.x + S0.y);   // lane holds p(qa+qq, k = kx*64+lane)
    float p1 = fast_exp2(S1.x + S1.y);
    float p2 = fast_exp2(S2.x + S2.y);
    float p3 = fast_exp2(S3.x + S3.y);

    // psum over this tile's 64 k
    float t0 = p0, t1 = p1, t2 = p2, t3 = p3;
    #pragma unroll
    for (int off = 32; off; off >>= 1) {
        t0 += __shfl_xor(t0, off);
        t1 += __shfl_xor(t1, off);
        t2 += __shfl_xor(t2, off);
        t3 += __shfl_xor(t3, off);
    }
    if (lane == 0) {
        if (ATOMIC) {
            atomicAdd(&psump[qa + 0], t0);
            atomicAdd(&psump[qa + 1], t1);
            atomicAdd(&psump[qa + 2], t2);
            atomicAdd(&psump[qa + 3], t3);
        } else {
            float* pp = psump + (size_t)kx * NROW + qa;
            pp[0] = t0; pp[1] = t1; pp[2] = t2; pp[3] = t3;
        }
    }

    // publish p[k] = {p0,p1,p2,p3} to the wave-private segment (this wave is
    // done reading its Eq rows; other waves never touch this segment, so no
    // barrier is needed — per-wave LDS ops are in order).
    *(float4*)&EqL[eqo + 4 * lane] = make_float4(p0, p1, p2, p3);

    // ---- pass B: o += p * V ; lane = d-pair, p via uniform LDS bcast;
    // packed v2f accumulate; bounded batches of 8 V-loads to avoid spill.
    const v2f* __restrict__ Vg =
        (const v2f*)(Vp + (size_t)b * (LL * DD) + (size_t)kx * 64 * DD);
    v2f o[4];
    #pragma unroll
    for (int qq = 0; qq < 4; ++qq) o[qq] = mk2(0.f, 0.f);

    #pragma unroll
    for (int g = 0; g < 8; ++g) {
        v2f v[8];
        #pragma unroll
        for (int e = 0; e < 8; ++e)
            v[e] = Vg[(size_t)(8 * g + e) * 64 + lane];   // coalesced batch
        #pragma unroll
        for (int e = 0; e < 8; ++e) {
            int kidx = 8 * g + e;
            float4 pw = *(const float4*)&EqL[eqo + 4 * kidx]; // bcast b128
            o[0] = fma2(mk2(pw.x, pw.x), v[e], o[0]);
            o[1] = fma2(mk2(pw.y, pw.y), v[e], o[1]);
            o[2] = fma2(mk2(pw.z, pw.z), v[e], o[2]);
            o[3] = fma2(mk2(pw.w, pw.w), v[e], o[3]);
        }
    }

    const int d2 = 2 * lane;
    if (ATOMIC) {
        #pragma unroll
        for (int qq = 0; qq < 4; ++qq) {
            atomicAdd(&outp[(size_t)(qa + qq) * DD + d2],     o[qq].x);
            atomicAdd(&outp[(size_t)(qa + qq) * DD + d2 + 1], o[qq].y);
        }
    } else {
        float* base = outp + (size_t)kx * MATN;
        #pragma unroll
        for (int qq = 0; qq < 4; ++qq)
            *(v2f*)&base[(size_t)(qa + qq) * DD + d2] = o[qq];
    }
}

// ---------------------------------------------------------------------------
// Fused reduce + normalize: out[q,d] = (sum_kx part[kx][q,d]) / (sum_kx psumP)
// float4-wide: 512 blocks x 256 threads over 131072 float4s.
// ---------------------------------------------------------------------------
__global__ __launch_bounds__(256) void reduce_kernel(
    const float* __restrict__ part, const float* __restrict__ psumP,
    float* __restrict__ out)
{
    int t = blockIdx.x * 256 + threadIdx.x;    // 131072 float4s
    const float4* p4 = (const float4*)part;
    float4 acc = make_float4(0.f, 0.f, 0.f, 0.f);
    #pragma unroll
    for (int kx = 0; kx < KSPLIT; ++kx) {
        float4 v = p4[(size_t)kx * (MATN / 4) + t];
        acc.x += v.x; acc.y += v.y; acc.z += v.z; acc.w += v.w;
    }
    int q = t >> 5;                            // 32 float4 per row
    float s = 0.f;
    #pragma unroll
    for (int kx = 0; kx < KSPLIT; ++kx) s += psumP[(size_t)kx * NROW + q];
    float inv = fast_rcp(s);
    ((float4*)out)[t] = make_float4(acc.x * inv, acc.y * inv,
                                    acc.z * inv, acc.w * inv);
}

// ---------------------------------------------------------------------------
__global__ __launch_bounds__(256) void norm_kernel(
    float* __restrict__ out, const float* __restrict__ psumG)
{
    int t = blockIdx.x * 256 + threadIdx.x;    // 262144 float2s
    float2* o2 = (float2*)out;
    int q = t >> 6;
    float inv = fast_rcp(psumG[q]);
    float2 v = o2[t];
    o2[t] = make_float2(v.x * inv, v.y * inv);
}

// ---------------------------------------------------------------------------
extern "C" void kernel_launch(void* const* d_in, const int* in_sizes, int n_in,
                              void* d_out, int out_size, void* d_ws, size_t ws_size,
                              hipStream_t stream) {
    const float* query = (const float*)d_in[0];
    const float* key_  = (const float*)d_in[1];
    const float* value = (const float*)d_in[2];
    const float* Wq    = (const float*)d_in[3];
    const float* bq    = (const float*)d_in[4];
    const float* Wk    = (const float*)d_in[5];
    const float* bk    = (const float*)d_in[6];
    const float* Wv    = (const float*)d_in[7];
    const float* bv    = (const float*)d_in[8];
    const float* wd    = (const float*)d_in[9];
    // d_in[10]/[12]/[14] = b_delta/b_sigma/b_theta: softmax-invariant, dropped
    const float* wsg   = (const float*)d_in[11];
    const float* wtt   = (const float*)d_in[13];
    float* ws = (float*)d_ws;
    float* out = (float*)d_out;

    // ws layout: Eq | Ek | V | w^(128) | psumP(8*NROW) | part(8*MATN)
    const size_t off_psum = (size_t)3 * MATN + 128;
    const size_t off_part = off_psum + (size_t)KSPLIT * NROW;
    const size_t need = (off_part + (size_t)KSPLIT * MATN) * sizeof(float);

    proj_kernel<<<384, 256, 0, stream>>>(query, key_, value,
                                         Wq, bq, Wk, bk, Wv, bv,
                                         wd, wsg, wtt, ws);
    if (ws_size >= need) {
        float* psumP = ws + off_psum;
        float* part  = ws + off_part;
        attn_kernel<false><<<1024, 512, 0, stream>>>(ws, part, psumP);
        reduce_kernel<<<512, 256, 0, stream>>>(part, psumP, out);
    } else {
        float* psumG = ws + off_psum;
        hipMemsetAsync(out, 0, (size_t)out_size * sizeof(float), stream);
        hipMemsetAsync(psumG, 0, (size_t)NROW * sizeof(float), stream);
        attn_kernel<true><<<1024, 512, 0, stream>>>(ws, out, psumG);
        norm_kernel<<<1024, 256, 0, stream>>>(out, psumG);
    }
}